// Round 2
// baseline (1536.994 us; speedup 1.0000x reference)
//
#include <hip/hip_runtime.h>
#include <math.h>

#define B_ 1024
#define V_ 5000
#define N_ 10000
#define T_ 50
#define H_ 200
#define K_ 20
#define EPS_ 1e-5f

typedef __attribute__((ext_vector_type(8))) short short8_t;
typedef __attribute__((ext_vector_type(4))) float float4_t;

__device__ __forceinline__ float sp_(float x) {
    return (x > 20.f) ? x : log1pf(expf(x));
}

__device__ __forceinline__ unsigned short f2bf(float x) {
    union { float f; unsigned int u; } c; c.f = x;
    unsigned int u = c.u + 0x7fffu + ((c.u >> 16) & 1u);
    return (unsigned short)(u >> 16);
}

// ---------------- init: zero the accumulators ----------------
__global__ __launch_bounds__(256) void k_init(float* e1a, float* e2a, float* Gacc,
                                              float* buckets, int* cnt) {
    int i = blockIdx.x * 256 + threadIdx.x;
    if (i < 640000)   Gacc[i] = 0.f;
    if (i < B_ * H_)  { e1a[i] = 0.f; e2a[i] = 0.f; }
    if (i < 1024)     buckets[i] = 0.f;
    if (i < 64)       cnt[i] = 0;
}

// ---------------- GEMM1: e1a += inputs @ W11^T  (fp32, ksplit atomics) ----------------
// grid (16, 25): 64 rows x 200 cols, Kc = 200, chunks of 20
__global__ __launch_bounds__(256) void k_gemm1(const float* __restrict__ X,
                                               const float* __restrict__ W,
                                               float* __restrict__ out) {
    __shared__ __align__(16) float Al[64][28];
    __shared__ __align__(16) float Bl[200][24];
    const int tid = threadIdx.x;
    const int tc = tid & 7, tr = tid >> 3;      // tc: 8 col-groups of 25, tr: 0..31 (2 rows each)
    const int m0 = blockIdx.x * 64;
    const int k0 = blockIdx.y * 200;
    float acc0[25], acc1[25];
#pragma unroll
    for (int j = 0; j < 25; ++j) { acc0[j] = 0.f; acc1[j] = 0.f; }
    for (int kb = 0; kb < 200; kb += 20) {
        __syncthreads();
        for (int i = tid; i < 320; i += 256) {
            int row = i / 5, q = i % 5;
            *(float4*)&Al[row][q * 4] = *(const float4*)&X[(size_t)(m0 + row) * V_ + k0 + kb + q * 4];
        }
        for (int i = tid; i < 1000; i += 256) {
            int row = i / 5, q = i % 5;
            *(float4*)&Bl[row][q * 4] = *(const float4*)&W[(size_t)row * V_ + k0 + kb + q * 4];
        }
        __syncthreads();
#pragma unroll
        for (int kq = 0; kq < 20; kq += 4) {
            float4 a0 = *(const float4*)&Al[2 * tr][kq];
            float4 a1 = *(const float4*)&Al[2 * tr + 1][kq];
#pragma unroll
            for (int j = 0; j < 25; ++j) {
                float4 b = *(const float4*)&Bl[tc * 25 + j][kq];
                acc0[j] += a0.x * b.x + a0.y * b.y + a0.z * b.z + a0.w * b.w;
                acc1[j] += a1.x * b.x + a1.y * b.y + a1.z * b.z + a1.w * b.w;
            }
        }
    }
#pragma unroll
    for (int j = 0; j < 25; ++j) {
        atomicAdd(&out[(size_t)(m0 + 2 * tr) * H_ + tc * 25 + j], acc0[j]);
        atomicAdd(&out[(size_t)(m0 + 2 * tr + 1) * H_ + tc * 25 + j], acc1[j]);
    }
}

// ---------------- softplus epilogue: out = softplus(acc + bias) ----------------
__global__ __launch_bounds__(256) void k_sp(const float* __restrict__ acc,
                                            const float* __restrict__ bias,
                                            float* __restrict__ out) {
    int i = blockIdx.x * 256 + threadIdx.x;
    if (i < B_ * H_) out[i] = sp_(acc[i] + bias[i % H_]);
}

// ---------------- GEMM2: e2a += e1 @ W12^T  (K=200, ksplit 2) ----------------
__global__ __launch_bounds__(256) void k_gemm2(const float* __restrict__ X,
                                               const float* __restrict__ W,
                                               float* __restrict__ out) {
    __shared__ __align__(16) float Al[64][28];
    __shared__ __align__(16) float Bl[200][24];
    const int tid = threadIdx.x;
    const int tc = tid & 7, tr = tid >> 3;
    const int m0 = blockIdx.x * 64;
    const int k0 = blockIdx.y * 100;
    float acc0[25], acc1[25];
#pragma unroll
    for (int j = 0; j < 25; ++j) { acc0[j] = 0.f; acc1[j] = 0.f; }
    for (int kb = 0; kb < 100; kb += 20) {
        __syncthreads();
        for (int i = tid; i < 320; i += 256) {
            int row = i / 5, q = i % 5;
            *(float4*)&Al[row][q * 4] = *(const float4*)&X[(size_t)(m0 + row) * H_ + k0 + kb + q * 4];
        }
        for (int i = tid; i < 1000; i += 256) {
            int row = i / 5, q = i % 5;
            *(float4*)&Bl[row][q * 4] = *(const float4*)&W[(size_t)row * H_ + k0 + kb + q * 4];
        }
        __syncthreads();
#pragma unroll
        for (int kq = 0; kq < 20; kq += 4) {
            float4 a0 = *(const float4*)&Al[2 * tr][kq];
            float4 a1 = *(const float4*)&Al[2 * tr + 1][kq];
#pragma unroll
            for (int j = 0; j < 25; ++j) {
                float4 b = *(const float4*)&Bl[tc * 25 + j][kq];
                acc0[j] += a0.x * b.x + a0.y * b.y + a0.z * b.z + a0.w * b.w;
                acc1[j] += a1.x * b.x + a1.y * b.y + a1.z * b.z + a1.w * b.w;
            }
        }
    }
#pragma unroll
    for (int j = 0; j < 25; ++j) {
        atomicAdd(&out[(size_t)(m0 + 2 * tr) * H_ + tc * 25 + j], acc0[j]);
        atomicAdd(&out[(size_t)(m0 + 2 * tr + 1) * H_ + tc * 25 + j], acc1[j]);
    }
}

// ---------------- GEMM3: thetalin = e2 @ W21^T + b21  (64x50 tile, K=200) ----------------
__global__ __launch_bounds__(128) void k_gemm3(const float* __restrict__ X,
                                               const float* __restrict__ W,
                                               const float* __restrict__ bias,
                                               float* __restrict__ out) {
    __shared__ __align__(16) float Al[64][28];
    __shared__ __align__(16) float Bl[50][24];
    const int tid = threadIdx.x;
    const int tc = tid & 1, tr = tid >> 1;      // tr 0..63, tc: 2 col-groups of 25
    const int m0 = blockIdx.x * 64;
    float acc[25];
#pragma unroll
    for (int j = 0; j < 25; ++j) acc[j] = 0.f;
    for (int kb = 0; kb < 200; kb += 20) {
        __syncthreads();
        for (int i = tid; i < 320; i += 128) {
            int row = i / 5, q = i % 5;
            *(float4*)&Al[row][q * 4] = *(const float4*)&X[(size_t)(m0 + row) * H_ + kb + q * 4];
        }
        for (int i = tid; i < 250; i += 128) {
            int row = i / 5, q = i % 5;
            *(float4*)&Bl[row][q * 4] = *(const float4*)&W[(size_t)row * H_ + kb + q * 4];
        }
        __syncthreads();
#pragma unroll
        for (int kq = 0; kq < 20; kq += 4) {
            float4 a0 = *(const float4*)&Al[tr][kq];
#pragma unroll
            for (int j = 0; j < 25; ++j) {
                float4 b = *(const float4*)&Bl[tc * 25 + j][kq];
                acc[j] += a0.x * b.x + a0.y * b.y + a0.z * b.z + a0.w * b.w;
            }
        }
    }
#pragma unroll
    for (int j = 0; j < 25; ++j)
        out[(size_t)(m0 + tr) * T_ + tc * 25 + j] = acc[j] + bias[tc * 25 + j];
}

// ---------------- BN stats for theta: one block per topic ----------------
__global__ __launch_bounds__(256) void k_bnstats(const float* __restrict__ th,
                                                 const float* __restrict__ g,
                                                 const float* __restrict__ be,
                                                 float* scale, float* shift) {
    __shared__ float r1[4], r2[4];
    const int t = blockIdx.x, tid = threadIdx.x;
    float s = 0.f, s2 = 0.f;
    for (int b = tid; b < B_; b += 256) {
        float x = th[b * T_ + t];
        s += x; s2 += x * x;
    }
#pragma unroll
    for (int off = 32; off; off >>= 1) { s += __shfl_xor(s, off); s2 += __shfl_xor(s2, off); }
    if ((tid & 63) == 0) { r1[tid >> 6] = s; r2[tid >> 6] = s2; }
    __syncthreads();
    if (tid == 0) {
        float S = r1[0] + r1[1] + r1[2] + r1[3];
        float S2 = r2[0] + r2[1] + r2[2] + r2[3];
        float mean = S * (1.f / B_);
        float var = S2 * (1.f / B_) - mean * mean;
        float sc = g[t] / sqrtf(var + EPS_);
        scale[t] = sc;
        shift[t] = be[t] - mean * sc;
    }
}

// ---------------- softmax(theta), argmax -> enc_idx, counts, quant_loss ----------------
__global__ __launch_bounds__(64) void k_st(const float* __restrict__ thetalin,
                                           const float* __restrict__ scale,
                                           const float* __restrict__ shift,
                                           float* __restrict__ st, float* __restrict__ stnorm,
                                           int* __restrict__ enc_idx, int* __restrict__ cnt,
                                           float* __restrict__ buckets) {
    const int b = blockIdx.x, t = threadIdx.x;
    float x = (t < T_) ? thetalin[b * T_ + t] * scale[t] + shift[t] : -INFINITY;
    float m = x;
#pragma unroll
    for (int off = 32; off; off >>= 1) m = fmaxf(m, __shfl_xor(m, off));
    float e = (t < T_) ? expf(x - m) : 0.f;
    float ssum = e;
#pragma unroll
    for (int off = 32; off; off >>= 1) ssum += __shfl_xor(ssum, off);
    float stv = e / ssum;
    if (t < T_) st[b * T_ + t] = stv;
    float sn = stv * stv;
#pragma unroll
    for (int off = 32; off; off >>= 1) sn += __shfl_xor(sn, off);
    float bv = x; int bi = (t < T_) ? t : (1 << 30);
#pragma unroll
    for (int off = 32; off; off >>= 1) {
        float ov = __shfl_xor(bv, off); int oi = __shfl_xor(bi, off);
        if (ov > bv || (ov == bv && oi < bi)) { bv = ov; bi = oi; }
    }
    if (t == 0) {
        enc_idx[b] = bi;
        atomicAdd(&cnt[bi], 1);
        stnorm[b] = sn;
        float stmax = 1.f / ssum;
        atomicAdd(&buckets[b], (1.25f / (float)(B_ * T_)) * (sn + 1.f - 2.f * stmax));
    }
}

// ---------------- decoder BN -> A rows (fp32) + bf16 B-matrix [64 x 5000] ----------------
__global__ __launch_bounds__(256) void k_amat(const float* __restrict__ Wd,
                                              const int* __restrict__ cnt,
                                              const float* __restrict__ gd,
                                              const float* __restrict__ bd,
                                              float* __restrict__ A,
                                              unsigned short* __restrict__ Bbf) {
    __shared__ float cl[T_];
    const int tid = threadIdx.x;
    if (tid < T_) cl[tid] = (float)cnt[tid];
    __syncthreads();
    int v = blockIdx.x * 256 + tid;
    if (v >= V_) return;
    float mean = 0.f, ex2 = 0.f;
#pragma unroll
    for (int t = 0; t < T_; ++t) {
        float w = Wd[v * T_ + t];
        mean += cl[t] * w; ex2 += cl[t] * w * w;
    }
    mean *= (1.f / B_); ex2 *= (1.f / B_);
    float rstd = 1.f / sqrtf(ex2 - mean * mean + EPS_);
    float g = gd[v], bb = bd[v];
#pragma unroll
    for (int t = 0; t < T_; ++t) {
        float val = (Wd[v * T_ + t] - mean) * rstd * g + bb;
        A[(size_t)t * V_ + v] = val;
        Bbf[(size_t)t * V_ + v] = f2bf(val);
    }
    Bbf[(size_t)50 * V_ + v] = 0x3F80u;   // bf16(1.0)
#pragma unroll
    for (int r = 51; r < 64; ++r) Bbf[(size_t)r * V_ + v] = 0u;
}

// ---------------- lse[t] = logsumexp_v A[t][v] ----------------
__global__ __launch_bounds__(256) void k_lse(const float* __restrict__ A, float* __restrict__ lse) {
    __shared__ float red[4];
    const int t = blockIdx.x, tid = threadIdx.x;
    const float* row = A + (size_t)t * V_;
    float m = -INFINITY;
    for (int i = tid; i < V_; i += 256) m = fmaxf(m, row[i]);
#pragma unroll
    for (int off = 32; off; off >>= 1) m = fmaxf(m, __shfl_xor(m, off));
    if ((tid & 63) == 0) red[tid >> 6] = m;
    __syncthreads();
    m = fmaxf(fmaxf(red[0], red[1]), fmaxf(red[2], red[3]));
    float s = 0.f;
    for (int i = tid; i < V_; i += 256) s += expf(row[i] - m);
#pragma unroll
    for (int off = 32; off; off >>= 1) s += __shfl_xor(s, off);
    __syncthreads();
    if ((tid & 63) == 0) red[tid >> 6] = s;
    __syncthreads();
    if (tid == 0) lse[t] = m + logf(red[0] + red[1] + red[2] + red[3]);
}

// ---------------- tbnorm[n] = ||theta_bank[n]||^2 ----------------
__global__ __launch_bounds__(256) void k_tbnorm(const float* __restrict__ tb, float* __restrict__ tbn) {
    int n = blockIdx.x * 256 + threadIdx.x;
    if (n >= N_) return;
    float s = 0.f;
#pragma unroll
    for (int t = 0; t < T_; ++t) { float x = tb[n * T_ + t]; s += x * x; }
    tbn[n] = s;
}

// ---------------- fused cost + fuse + per-half top-20 ----------------
__global__ __launch_bounds__(256) void k_fuse_topk(const float* __restrict__ st,
                                                   const float* __restrict__ stnorm,
                                                   const float* __restrict__ tb,
                                                   const float* __restrict__ tbn,
                                                   const float* __restrict__ Mcos,
                                                   const float* __restrict__ Mcoo,
                                                   const int* __restrict__ idx,
                                                   float* __restrict__ cand_v,
                                                   int* __restrict__ cand_i) {
    __shared__ __align__(16) float tbl[256 * T_];
    const int tid = threadIdx.x;
    const int lane = tid & 63, wv = tid >> 6;
    const int half = blockIdx.x & 1;
    const int r = (blockIdx.x >> 1) * 4 + wv;
    const int n0 = half * 5000;
    float sreg[T_];
#pragma unroll
    for (int k = 0; k < T_; ++k) sreg[k] = st[r * T_ + k];
    const float snr = stnorm[r];
    const int myidx = idx[r];
    const float* mcr = Mcos + (size_t)myidx * N_;
    const float* mor = Mcoo + (size_t)myidx * N_;
    float tv[K_]; int ti[K_];
#pragma unroll
    for (int s = 0; s < K_; ++s) { tv[s] = INFINITY; ti[s] = -1; }
    float worst = INFINITY;
    for (int c0 = 0; c0 < 5000; c0 += 256) {
        int nrows = min(256, 5000 - c0);
        __syncthreads();
        {
            const float4* src = (const float4*)(tb + (size_t)(n0 + c0) * T_);
            float4* dst = (float4*)tbl;
            int cnt4 = nrows * T_ / 4;
            for (int i = tid; i < cnt4; i += 256) dst[i] = src[i];
        }
        __syncthreads();
#pragma unroll
        for (int jj = 0; jj < 4; ++jj) {
            int nn = lane + 64 * jj;
            int n = n0 + c0 + nn;
            if (nn < nrows && n != myidx) {
                const float2* t2 = (const float2*)(tbl + nn * T_);
                float d = 0.f;
#pragma unroll
                for (int k = 0; k < T_ / 2; ++k) {
                    float2 w = t2[k];
                    d += sreg[2 * k] * w.x + sreg[2 * k + 1] * w.y;
                }
                float cost = snr + tbn[n] - 2.f * d;
                float f = 0.5f * cost * cost + 0.5f * (0.5f * mcr[n] + 0.5f * mor[n]);
                if (f < worst) {
                    bool done = false;
#pragma unroll
                    for (int s = 0; s < K_; ++s) {
                        bool mm = (!done) && (tv[s] == worst);
                        if (mm) { tv[s] = f; ti[s] = n; done = true; }
                    }
                    worst = tv[0];
#pragma unroll
                    for (int s = 1; s < K_; ++s) worst = fmaxf(worst, tv[s]);
                }
            }
        }
    }
    for (int it = 0; it < K_; ++it) {
        float mv = INFINITY; int mi = -1, ms = -1;
#pragma unroll
        for (int s = 0; s < K_; ++s) {
            bool better = tv[s] < mv;
            mv = better ? tv[s] : mv;
            mi = better ? ti[s] : mi;
            ms = better ? s : ms;
        }
        float bv = mv; int bn = mi, bl = lane, bs = ms;
#pragma unroll
        for (int off = 32; off; off >>= 1) {
            float ov = __shfl_xor(bv, off); int on = __shfl_xor(bn, off);
            int ol = __shfl_xor(bl, off);   int os = __shfl_xor(bs, off);
            if (ov < bv || (ov == bv && on < bn)) { bv = ov; bn = on; bl = ol; bs = os; }
        }
        if (lane == 0) {
            cand_v[(r * 2 + half) * K_ + it] = bv;
            cand_i[(r * 2 + half) * K_ + it] = bn;
        }
        if (lane == bl) {
#pragma unroll
            for (int s = 0; s < K_; ++s)
                if (s == bs) tv[s] = INFINITY;
        }
    }
}

// ---------------- merge two per-half top-20 lists ----------------
__global__ __launch_bounds__(64) void k_merge40(const float* __restrict__ cand_v,
                                                const int* __restrict__ cand_i,
                                                int* __restrict__ topk) {
    const int b = blockIdx.x, lane = threadIdx.x;
    float v = (lane < 2 * K_) ? cand_v[b * 2 * K_ + lane] : INFINITY;
    int id = (lane < 2 * K_) ? cand_i[b * 2 * K_ + lane] : -1;
    for (int it = 0; it < K_; ++it) {
        float bv = v; int bn = id, bl = lane;
#pragma unroll
        for (int off = 32; off; off >>= 1) {
            float ov = __shfl_xor(bv, off); int on = __shfl_xor(bn, off);
            int ol = __shfl_xor(bl, off);
            if (ov < bv || (ov == bv && on < bn)) { bv = ov; bn = on; bl = ol; }
        }
        if (lane == 0) topk[b * K_ + it] = bn;
        if (lane == bl) v = INFINITY;
    }
}

// ---------------- G = td @ [A;1]^T via bf16 MFMA, on-the-fly conversion ----------------
// grid (79, 4): 128-row M-tile, ksplit 4 (Kc=1280 padded, guard k<5000), 40 chunks of 32
__global__ __launch_bounds__(256) void k_gmm(const float* __restrict__ td,
                                             const unsigned short* __restrict__ Bbf,
                                             float* __restrict__ Gacc) {
    __shared__ __align__(16) unsigned short At[128][40];
    __shared__ __align__(16) unsigned short Bt[64][40];
    const int tid = threadIdx.x;
    const int lane = tid & 63, w = tid >> 6;
    const int lm = lane & 15, kg = lane >> 4;
    const int m0 = blockIdx.x * 128;
    const int ks = blockIdx.y * 1280;
    float4_t acc[8];
#pragma unroll
    for (int mt = 0; mt < 8; ++mt)
#pragma unroll
        for (int r = 0; r < 4; ++r) acc[mt][r] = 0.f;

    const int arow = tid >> 1, ahf = tid & 1;       // A stage: 128 rows x 2 halves of 16
    const int brow = tid >> 2, bq = tid & 3;        // B stage: 64 rows x 4 groups of 8

    for (int ch = 0; ch < 40; ++ch) {
        const int kk = ks + ch * 32;
        __syncthreads();
        {   // stage A: fp32 -> bf16
            const size_t base = (size_t)(m0 + arow) * V_ + kk + ahf * 16;
            unsigned int p[8];
            bool rok = (m0 + arow) < N_;
#pragma unroll
            for (int q = 0; q < 4; ++q) {
                float4 x = (rok && (kk + ahf * 16 + q * 4) < V_)
                           ? *(const float4*)&td[base + q * 4]
                           : make_float4(0.f, 0.f, 0.f, 0.f);
                p[q * 2]     = (unsigned int)f2bf(x.x) | ((unsigned int)f2bf(x.y) << 16);
                p[q * 2 + 1] = (unsigned int)f2bf(x.z) | ((unsigned int)f2bf(x.w) << 16);
            }
            *(uint4*)&At[arow][ahf * 16]     = *(uint4*)&p[0];
            *(uint4*)&At[arow][ahf * 16 + 8] = *(uint4*)&p[4];
        }
        {   // stage B (already bf16)
            uint4 bv = make_uint4(0, 0, 0, 0);
            if ((kk + bq * 8) < V_)
                bv = *(const uint4*)&Bbf[(size_t)brow * V_ + kk + bq * 8];
            *(uint4*)&Bt[brow][bq * 8] = bv;
        }
        __syncthreads();
        short8_t bfrag = *(const short8_t*)&Bt[16 * w + lm][kg * 8];
#pragma unroll
        for (int mt = 0; mt < 8; ++mt) {
            short8_t afrag = *(const short8_t*)&At[16 * mt + lm][kg * 8];
            acc[mt] = __builtin_amdgcn_mfma_f32_16x16x32_bf16(afrag, bfrag, acc[mt], 0, 0, 0);
        }
    }
    const int col = 16 * w + lm;
#pragma unroll
    for (int mt = 0; mt < 8; ++mt) {
#pragma unroll
        for (int r = 0; r < 4; ++r) {
            int row = m0 + 16 * mt + kg * 4 + r;
            if (row < N_) atomicAdd(&Gacc[(size_t)row * 64 + col], acc[mt][r]);
        }
    }
}

// ---------------- aug rec term from G lookups ----------------
__global__ __launch_bounds__(64) void k_augnew(const float* __restrict__ Gacc,
                                               const float* __restrict__ lse,
                                               const int* __restrict__ topk,
                                               const int* __restrict__ enc_idx,
                                               const int* __restrict__ flag,
                                               float* __restrict__ buckets) {
    const int b = blockIdx.x, l = threadIdx.x;
    const int t = enc_idx[b];
    float v = 0.f;
    if (l < K_) {
        int j = topk[b * K_ + l];
        v = lse[t] * Gacc[(size_t)j * 64 + 50] - Gacc[(size_t)j * 64 + t];
    }
#pragma unroll
    for (int off = 32; off; off >>= 1) v += __shfl_xor(v, off);
    if (l == 0 && *flag != 0)
        atomicAdd(&buckets[b], v * (1.f / ((float)B_ * (float)K_)));
}

// ---------------- inputs part of rec_loss ----------------
__global__ __launch_bounds__(256) void k_xin(const float* __restrict__ inputs,
                                             const float* __restrict__ A,
                                             const float* __restrict__ lse,
                                             const int* __restrict__ enc_idx,
                                             float* __restrict__ buckets) {
    __shared__ float red[8];
    const int tid = threadIdx.x, b = blockIdx.x;
    const int t = enc_idx[b];
    const float4* xr = (const float4*)(inputs + (size_t)b * V_);
    const float4* ar = (const float4*)(A + (size_t)t * V_);
    float dot = 0.f, s = 0.f;
    for (int i = tid; i < V_ / 4; i += 256) {
        float4 a = xr[i]; float4 wv = ar[i];
        dot += a.x * wv.x + a.y * wv.y + a.z * wv.z + a.w * wv.w;
        s += a.x + a.y + a.z + a.w;
    }
#pragma unroll
    for (int off = 32; off; off >>= 1) {
        dot += __shfl_xor(dot, off);
        s += __shfl_xor(s, off);
    }
    if ((tid & 63) == 0) { red[(tid >> 6) * 2] = dot; red[(tid >> 6) * 2 + 1] = s; }
    __syncthreads();
    if (tid == 0) {
        float D = red[0] + red[2] + red[4] + red[6];
        float S = red[1] + red[3] + red[5] + red[7];
        atomicAdd(&buckets[b], (lse[t] * S - D) * (1.f / (float)B_));
    }
}

// ---------------- final reduce ----------------
__global__ __launch_bounds__(256) void k_final(const float* __restrict__ buckets, float* __restrict__ out) {
    __shared__ float red[4];
    const int tid = threadIdx.x;
    float v = buckets[tid] + buckets[tid + 256] + buckets[tid + 512] + buckets[tid + 768];
#pragma unroll
    for (int off = 32; off; off >>= 1) v += __shfl_xor(v, off);
    if ((tid & 63) == 0) red[tid >> 6] = v;
    __syncthreads();
    if (tid == 0) out[0] = red[0] + red[1] + red[2] + red[3];
}

extern "C" void kernel_launch(void* const* d_in, const int* in_sizes, int n_in,
                              void* d_out, int out_size, void* d_ws, size_t ws_size,
                              hipStream_t stream) {
    const int*   idx    = (const int*)d_in[0];
    const float* inputs = (const float*)d_in[1];
    const int*   flag   = (const int*)d_in[2];
    const float* td     = (const float*)d_in[3];
    const float* Mcos   = (const float*)d_in[4];
    const float* Mcoo   = (const float*)d_in[5];
    const float* tb     = (const float*)d_in[6];
    const float* W11    = (const float*)d_in[7];
    const float* b11    = (const float*)d_in[8];
    const float* W12    = (const float*)d_in[9];
    const float* b12    = (const float*)d_in[10];
    const float* W21    = (const float*)d_in[11];
    const float* b21    = (const float*)d_in[12];
    const float* gm     = (const float*)d_in[13];
    const float* bm     = (const float*)d_in[14];
    const float* gd     = (const float*)d_in[15];
    const float* bd     = (const float*)d_in[16];
    const float* Wd     = (const float*)d_in[17];
    float* out = (float*)d_out;

    float* ws       = (float*)d_ws;
    float* e1a      = ws;                       // 204800
    float* e1       = e1a + 204800;             // 204800
    float* e2a      = e1 + 204800;              // 204800
    float* e2       = e2a + 204800;             // 204800
    float* thetalin = e2 + 204800;              // 51200
    float* st       = thetalin + 51200;         // 51200
    float* stnorm   = st + 51200;               // 1024
    float* scale    = stnorm + 1024;            // 64
    float* shift    = scale + 64;               // 64
    float* Amat     = shift + 64;               // 250000
    float* lse      = Amat + 250000;            // 64
    float* tbn      = lse + 64;                 // 10000
    float* buckets  = tbn + 10000;              // 1024
    float* cand_v   = buckets + 1024;           // 40960
    float* Gacc     = cand_v + 40960;           // 640000
    unsigned short* Bbf = (unsigned short*)(Gacc + 640000);   // 320000 ushort = 160000 f
    int*   enc_idx  = (int*)(Gacc + 640000 + 160000);         // 1024
    int*   cnt      = enc_idx + 1024;           // 64
    int*   cand_i   = cnt + 64;                 // 40960
    int*   topk     = cand_i + 40960;           // 20480

    k_init<<<2500, 256, 0, stream>>>(e1a, e2a, Gacc, buckets, cnt);
    k_gemm1<<<dim3(16, 25), 256, 0, stream>>>(inputs, W11, e1a);
    k_sp<<<800, 256, 0, stream>>>(e1a, b11, e1);
    k_gemm2<<<dim3(16, 2), 256, 0, stream>>>(e1, W12, e2a);
    k_sp<<<800, 256, 0, stream>>>(e2a, b12, e2);
    k_gemm3<<<16, 128, 0, stream>>>(e2, W21, b21, thetalin);
    k_bnstats<<<50, 256, 0, stream>>>(thetalin, gm, bm, scale, shift);
    k_st<<<1024, 64, 0, stream>>>(thetalin, scale, shift, st, stnorm, enc_idx, cnt, buckets);
    k_amat<<<20, 256, 0, stream>>>(Wd, cnt, gd, bd, Amat, Bbf);
    k_lse<<<50, 256, 0, stream>>>(Amat, lse);
    k_tbnorm<<<40, 256, 0, stream>>>(tb, tbn);
    k_fuse_topk<<<512, 256, 0, stream>>>(st, stnorm, tb, tbn, Mcos, Mcoo, idx, cand_v, cand_i);
    k_merge40<<<1024, 64, 0, stream>>>(cand_v, cand_i, topk);
    k_gmm<<<dim3(79, 4), 256, 0, stream>>>(td, Bbf, Gacc);
    k_augnew<<<1024, 64, 0, stream>>>(Gacc, lse, topk, enc_idx, flag, buckets);
    k_xin<<<1024, 256, 0, stream>>>(inputs, Amat, lse, enc_idx, buckets);
    k_final<<<1, 256, 0, stream>>>(buckets, out);
}